// Round 9
// baseline (53.865 us; speedup 1.0000x reference)
//
#include <hip/hip_runtime.h>
#include <math.h>

#define DDIM 512
#define THREADS 256
#define BT 64           // block tile (M and N)
#define BK 64           // K-step (one staged LDS tile)
#define NT 64           // N / BT tile grid dimension
#define NTILES (NT * (NT + 1) / 2)   // 2080 triangular tiles (divisible by 8)
#define NCH 64          // 64-wide column chunks for partials

typedef __attribute__((ext_vector_type(8))) __bf16 bf16x8;
typedef __attribute__((ext_vector_type(4))) float f32x4;
typedef __attribute__((ext_vector_type(8))) unsigned short ushort8;

__device__ __forceinline__ float bf2f(unsigned short u) {
  union { unsigned int i; float f; } v; v.i = ((unsigned int)u) << 16; return v.f;
}
__device__ __forceinline__ unsigned short f2bf(float f) {
  unsigned int u = __builtin_bit_cast(unsigned int, f);
  return (unsigned short)((u + 0x7fffu + ((u >> 16) & 1u)) >> 16);
}

#define GLOAD_LDS16(gp, lp)                                                   \
  __builtin_amdgcn_global_load_lds(                                           \
      (const __attribute__((address_space(1))) unsigned int*)(gp),            \
      (__attribute__((address_space(3))) unsigned int*)(lp), 16, 0, 0)

// ---- kernel 1: normalize rows w and w+B to bf16, compute pos[w]=dot/temp ----
__global__ void k_prep(const float* __restrict__ zi, const float* __restrict__ zj,
                       const float* __restrict__ tempp,
                       unsigned short* __restrict__ znb, float* __restrict__ pos,
                       int B) {
  int wv = (blockIdx.x * blockDim.x + threadIdx.x) >> 6;
  int lane = threadIdx.x & 63;
  if (wv >= B) return;
  const float* a = zi + (size_t)wv * DDIM;
  const float* b = zj + (size_t)wv * DDIM;
  float4 a0 = *(const float4*)(a + lane * 8);
  float4 a1 = *(const float4*)(a + lane * 8 + 4);
  float4 b0 = *(const float4*)(b + lane * 8);
  float4 b1 = *(const float4*)(b + lane * 8 + 4);
  float av[8] = {a0.x, a0.y, a0.z, a0.w, a1.x, a1.y, a1.z, a1.w};
  float bv[8] = {b0.x, b0.y, b0.z, b0.w, b1.x, b1.y, b1.z, b1.w};
  float sa = 0.f, sb = 0.f;
#pragma unroll
  for (int i = 0; i < 8; ++i) { sa = fmaf(av[i], av[i], sa); sb = fmaf(bv[i], bv[i], sb); }
#pragma unroll
  for (int off = 32; off; off >>= 1) { sa += __shfl_xor(sa, off, 64); sb += __shfl_xor(sb, off, 64); }
  float ia = 1.f / fmaxf(sqrtf(sa), 1e-8f);
  float ib = 1.f / fmaxf(sqrtf(sb), 1e-8f);
  ushort8 ua, ub;
  float fa[8], fb[8];
#pragma unroll
  for (int i = 0; i < 8; ++i) {
    unsigned short x = f2bf(av[i] * ia); ua[i] = x; fa[i] = bf2f(x);
    unsigned short y = f2bf(bv[i] * ib); ub[i] = y; fb[i] = bf2f(y);
  }
  *(ushort8*)(znb + (size_t)wv * DDIM + lane * 8) = ua;
  *(ushort8*)(znb + (size_t)(wv + B) * DDIM + lane * 8) = ub;
  float pd = 0.f;
#pragma unroll
  for (int i = 0; i < 8; ++i) pd = fmaf(fa[i], fb[i], pd);
#pragma unroll
  for (int off = 32; off; off >>= 1) pd += __shfl_xor(pd, off, 64);
  if (lane == 0) {
    float p = pd / tempp[0];
    pos[wv] = p; pos[wv + B] = p;
  }
}

// stage one 64x64 bf16 panel (8 KB) into LDS; 8 regions of 8 rows x 8 slots
__device__ __forceinline__ void stage_tile(const unsigned short* __restrict__ znb,
                                           int panel0, int k0, unsigned char* dst,
                                           int wave, int lane) {
  const int srow_in = lane >> 3;                  // 0..7 within 8-row region
  const int slog = (lane & 7) ^ srow_in;          // logical 16B k-slot (involution)
#pragma unroll
  for (int j = 0; j < 2; ++j) {
    const int ww = wave * 2 + j;                  // region 0..7
    const int row = 8 * ww + srow_in;
    GLOAD_LDS16(znb + (size_t)(panel0 + row) * DDIM + k0 + slog * 8, dst + ww * 1024);
  }
}

// ---- kernel 2: symmetric Gram tiles; A resident in registers, B-only LDS ---
__global__ __launch_bounds__(THREADS) void k_main(
    const unsigned short* __restrict__ znb, const float* __restrict__ pos,
    const float* __restrict__ tempp, float* __restrict__ partS,
    float* __restrict__ partC, int B) {
  // XCD-aware bijective swizzle (2080 = 8 * 260)
  int tri = (blockIdx.x & 7) * (NTILES / 8) + (blockIdx.x >> 3);
  // decode upper-triangular tile (bi <= bj)
  int bi = 0;
  while (tri >= NT - bi) { tri -= NT - bi; ++bi; }
  const int bj = bi + tri;
  const int r0 = bi * BT, c0 = bj * BT;
  const bool diag = (bi == bj);
  const float invt = 1.0f / tempp[0];

  __shared__ __align__(16) unsigned char sB[BT * BK * 2];  // 8 KB (B panel only)

  const int t = threadIdx.x;
  const int lane = t & 63;
  const int wave = t >> 6;                   // wave owns rows r0+wave*16 .. +15
  const int cl = lane & 15, g = lane >> 4;

  // ---- A fragments for the wave's 16 rows, ALL of K, in registers ----
  // frag s covers k = s*32 + g*8 .. +7 for row r0+wave*16+cl  (same element
  // mapping as the LDS-read path used in rounds 2-8 -> bit-identical MFMA)
  const unsigned short* aBase = znb + (size_t)(r0 + wave * 16 + cl) * DDIM + g * 8;
  bf16x8 aR[16];
#pragma unroll
  for (int s = 0; s < 16; ++s)
    aR[s] = *(const bf16x8*)(aBase + s * 32);

  f32x4 acc[4];
#pragma unroll
  for (int n = 0; n < 4; ++n) acc[n] = (f32x4){0.f, 0.f, 0.f, 0.f};

#pragma unroll
  for (int kt = 0; kt < DDIM / BK; ++kt) {   // 8 K-tiles; only B is staged
    stage_tile(znb, c0, kt * BK, sB, wave, lane);
    __syncthreads();                          // DMA drained, sB ready
#pragma unroll
    for (int ks = 0; ks < 2; ++ks) {
      const int phys = (g + ks * 4) ^ (cl & 7);
      bf16x8 bF[4];
#pragma unroll
      for (int n = 0; n < 4; ++n)
        bF[n] = *(const bf16x8*)(sB + (n * 16 + cl) * 128 + phys * 16);
#pragma unroll
      for (int n = 0; n < 4; ++n)
        acc[n] = __builtin_amdgcn_mfma_f32_16x16x32_bf16(aR[kt * 2 + ks], bF[n], acc[n], 0, 0, 0);
    }
    __syncthreads();                          // all reads done before overwrite
  }

  // ---- epilogue: fused exp-sum / rank-count, both directions ----
  int growv[4], gpartr[4];
  float pvr[4];
#pragma unroll
  for (int reg = 0; reg < 4; ++reg) {
    int grow = r0 + wave * 16 + g * 4 + reg;
    growv[reg] = grow;
    gpartr[reg] = (grow < B) ? grow + B : grow - B;
    pvr[reg] = pos[grow];
  }
  int gcolv[4], gpartc[4];
  float pvc[4];
#pragma unroll
  for (int n = 0; n < 4; ++n) {
    int gcol = c0 + n * 16 + cl;
    gcolv[n] = gcol;
    gpartc[n] = (gcol < B) ? gcol + B : gcol - B;
    pvc[n] = pos[gcol];
  }

  float ssr[4], ccr[4], ssc[4], ccc[4];
#pragma unroll
  for (int i = 0; i < 4; ++i) { ssr[i] = 0.f; ccr[i] = 0.f; ssc[i] = 0.f; ccc[i] = 0.f; }

#pragma unroll
  for (int n = 0; n < 4; ++n)
#pragma unroll
    for (int reg = 0; reg < 4; ++reg) {
      float val = acc[n][reg] * invt;
      float e = __expf(val);
      bool isd = diag && (gcolv[n] == growv[reg]);
      if (!isd) {
        ssr[reg] += e;
        ccr[reg] += (gcolv[n] != gpartr[reg] && val > pvr[reg]) ? 1.f : 0.f;
      }
      if (!diag) {
        ssc[n] += e;
        ccc[n] += (growv[reg] != gpartc[n] && val > pvc[n]) ? 1.f : 0.f;
      }
    }

  // row partials: each wave owns complete rows -> reduce over cl only
#pragma unroll
  for (int reg = 0; reg < 4; ++reg) {
    float s = ssr[reg], c = ccr[reg];
#pragma unroll
    for (int off = 1; off < 16; off <<= 1) {
      s += __shfl_xor(s, off, 64);
      c += __shfl_xor(c, off, 64);
    }
    if (cl == 0) {
      partS[(size_t)growv[reg] * NCH + bj] = s;
      partC[(size_t)growv[reg] * NCH + bj] = c;
    }
  }

  // col partials: reduce over g in-wave, then cross-wave combine via LDS
  if (!diag) {
#pragma unroll
    for (int n = 0; n < 4; ++n) {
      ssc[n] += __shfl_xor(ssc[n], 16, 64); ccc[n] += __shfl_xor(ccc[n], 16, 64);
      ssc[n] += __shfl_xor(ssc[n], 32, 64); ccc[n] += __shfl_xor(ccc[n], 32, 64);
    }
    float* colS = (float*)sB;                 // [4 waves][64 cols]
    float* colC = colS + 256;
    if (g == 0) {
#pragma unroll
      for (int n = 0; n < 4; ++n) {
        colS[wave * 64 + n * 16 + cl] = ssc[n];
        colC[wave * 64 + n * 16 + cl] = ccc[n];
      }
    }
    __syncthreads();
    if (t < 64) {
      float s = colS[t] + colS[64 + t] + colS[128 + t] + colS[192 + t];
      float c = colC[t] + colC[64 + t] + colC[128 + t] + colC[192 + t];
      partS[(size_t)(c0 + t) * NCH + bi] = s;
      partC[(size_t)(c0 + t) * NCH + bi] = c;
    }
  }
}

// ---- kernel 3: per-row combine of 64 chunks -> rowLoss, rowCnt ----
__global__ void k_rowfin(const float* __restrict__ partS, const float* __restrict__ partC,
                         const float* __restrict__ pos, float* __restrict__ rowL,
                         float* __restrict__ rowC, int N) {
  int r = (blockIdx.x * blockDim.x + threadIdx.x) >> 6;
  int lane = threadIdx.x & 63;
  if (r >= N) return;
  float s = partS[(size_t)r * NCH + lane];
  float c = partC[(size_t)r * NCH + lane];
#pragma unroll
  for (int off = 32; off; off >>= 1) { s += __shfl_xor(s, off, 64); c += __shfl_xor(c, off, 64); }
  if (lane == 0) {
    rowL[r] = logf(s) - pos[r];
    rowC[r] = c;
  }
}

// ---- kernel 4: final reduction to (loss, avg_rank) ----
__global__ void k_final(const float* __restrict__ rowL, const float* __restrict__ rowC,
                        float* __restrict__ out, int N) {
  float ls = 0.f, cs = 0.f;
  for (int r = threadIdx.x; r < N; r += THREADS) { ls += rowL[r]; cs += rowC[r]; }
  __shared__ float l[THREADS], c[THREADS];
  l[threadIdx.x] = ls; c[threadIdx.x] = cs;
  __syncthreads();
  for (int off = THREADS / 2; off; off >>= 1) {
    if (threadIdx.x < off) { l[threadIdx.x] += l[threadIdx.x + off]; c[threadIdx.x] += c[threadIdx.x + off]; }
    __syncthreads();
  }
  if (threadIdx.x == 0) { out[0] = l[0] / (float)N; out[1] = c[0] / (float)N; }
}

extern "C" void kernel_launch(void* const* d_in, const int* in_sizes, int n_in,
                              void* d_out, int out_size, void* d_ws, size_t ws_size,
                              hipStream_t stream) {
  const float* zi = (const float*)d_in[0];
  const float* zj = (const float*)d_in[1];
  const float* temp = (const float*)d_in[2];
  float* out = (float*)d_out;

  const int B = in_sizes[0] / DDIM;   // 2048
  const int N = 2 * B;                // 4096

  unsigned short* znb = (unsigned short*)d_ws;          // N*DDIM bf16 = 4 MB
  float* fws = (float*)(znb + (size_t)N * DDIM);
  float* pos   = fws;                                    // N
  float* partS = pos + N;                                // N*NCH = 1 MB
  float* partC = partS + (size_t)N * NCH;                // N*NCH = 1 MB
  float* rowL  = partC + (size_t)N * NCH;                // N
  float* rowC  = rowL + N;                               // N

  k_prep<<<(B * 64) / THREADS, THREADS, 0, stream>>>(zi, zj, temp, znb, pos, B);
  k_main<<<NTILES, THREADS, 0, stream>>>(znb, pos, temp, partS, partC, B);
  k_rowfin<<<(N * 64) / THREADS, THREADS, 0, stream>>>(partS, partC, pos, rowL, rowC, N);
  k_final<<<1, THREADS, 0, stream>>>(rowL, rowC, out, N);
}

// Round 10
// 41.936 us; speedup vs baseline: 1.2845x; 1.2845x over previous
//
#include <hip/hip_runtime.h>
#include <math.h>

#define DDIM 512
#define THREADS 128     // 2 waves per block
#define BT 64           // block tile (M and N)
#define NT 64           // N / BT tile grid dimension
#define NTILES (NT * (NT + 1) / 2)   // 2080 triangular tiles (divisible by 8)
#define NSL 16          // K slices of 32 (DDIM/32)
#define NCH 64          // 64-wide column chunks for partials

typedef __attribute__((ext_vector_type(8))) __bf16 bf16x8;
typedef __attribute__((ext_vector_type(4))) float f32x4;
typedef __attribute__((ext_vector_type(8))) unsigned short ushort8;

__device__ __forceinline__ float bf2f(unsigned short u) {
  union { unsigned int i; float f; } v; v.i = ((unsigned int)u) << 16; return v.f;
}
__device__ __forceinline__ unsigned short f2bf(float f) {
  unsigned int u = __builtin_bit_cast(unsigned int, f);
  return (unsigned short)((u + 0x7fffu + ((u >> 16) & 1u)) >> 16);
}

// fragment-major layout: frag (rt, s) = rows rt*16..+15, k = s*32..+31.
// within frag: lane (g<<4)|cl holds row rt*16+cl, k s*32+g*8..+7 (16 B).
// byte offset = ((rt*16 + s)*64 + lane) * 16  -> 1 KB contiguous per frag.
__device__ __forceinline__ size_t frag_off_us(int rt, int s, int lane) {
  return ((size_t)(rt * NSL + s) * 64 + lane) * 8;   // in ushorts
}

// ---- kernel 1: normalize rows w and w+B to bf16 frag layout, pos[w] --------
__global__ void k_prep(const float* __restrict__ zi, const float* __restrict__ zj,
                       const float* __restrict__ tempp,
                       unsigned short* __restrict__ zf, float* __restrict__ pos,
                       int B) {
  int wv = (blockIdx.x * blockDim.x + threadIdx.x) >> 6;
  int lane = threadIdx.x & 63;
  if (wv >= B) return;
  const float* a = zi + (size_t)wv * DDIM;
  const float* b = zj + (size_t)wv * DDIM;
  float4 a0 = *(const float4*)(a + lane * 8);
  float4 a1 = *(const float4*)(a + lane * 8 + 4);
  float4 b0 = *(const float4*)(b + lane * 8);
  float4 b1 = *(const float4*)(b + lane * 8 + 4);
  float av[8] = {a0.x, a0.y, a0.z, a0.w, a1.x, a1.y, a1.z, a1.w};
  float bv[8] = {b0.x, b0.y, b0.z, b0.w, b1.x, b1.y, b1.z, b1.w};
  float sa = 0.f, sb = 0.f;
#pragma unroll
  for (int i = 0; i < 8; ++i) { sa = fmaf(av[i], av[i], sa); sb = fmaf(bv[i], bv[i], sb); }
#pragma unroll
  for (int off = 32; off; off >>= 1) { sa += __shfl_xor(sa, off, 64); sb += __shfl_xor(sb, off, 64); }
  float ia = 1.f / fmaxf(sqrtf(sa), 1e-8f);
  float ib = 1.f / fmaxf(sqrtf(sb), 1e-8f);
  ushort8 ua, ub;
  float fa[8], fb[8];
#pragma unroll
  for (int i = 0; i < 8; ++i) {
    unsigned short x = f2bf(av[i] * ia); ua[i] = x; fa[i] = bf2f(x);
    unsigned short y = f2bf(bv[i] * ib); ub[i] = y; fb[i] = bf2f(y);
  }
  // lane covers k = lane*8..+7  ->  slice s = lane>>2, sub g = lane&3
  const int s = lane >> 2, g = lane & 3;
  {
    int r = wv;                                  // row wv
    *(ushort8*)(zf + frag_off_us(r >> 4, s, (g << 4) | (r & 15))) = ua;
    r = wv + B;                                  // row wv+B
    *(ushort8*)(zf + frag_off_us(r >> 4, s, (g << 4) | (r & 15))) = ub;
  }
  float pd = 0.f;
#pragma unroll
  for (int i = 0; i < 8; ++i) pd = fmaf(fa[i], fb[i], pd);
#pragma unroll
  for (int off = 32; off; off >>= 1) pd += __shfl_xor(pd, off, 64);
  if (lane == 0) {
    float p = pd / tempp[0];
    pos[wv] = p; pos[wv + B] = p;
  }
}

// ---- kernel 2: barrier-free MFMA Gram tiles from fragment-major global -----
__global__ __launch_bounds__(THREADS) void k_main(
    const unsigned short* __restrict__ zf, const float* __restrict__ pos,
    const float* __restrict__ tempp, float* __restrict__ partS,
    float* __restrict__ partC, int B) {
  // XCD-aware bijective swizzle (2080 = 8 * 260)
  int tri = (blockIdx.x & 7) * (NTILES / 8) + (blockIdx.x >> 3);
  int bi = 0;
  while (tri >= NT - bi) { tri -= NT - bi; ++bi; }
  const int bj = bi + tri;
  const int r0 = bi * BT, c0 = bj * BT;
  const bool diag = (bi == bj);
  const float invt = 1.0f / tempp[0];

  const int t = threadIdx.x;
  const int lane = t & 63;
  const int wave = t >> 6;                   // wave owns rows r0+wave*32..+31
  const int cl = lane & 15, g = lane >> 4;

  const int art0 = (r0 >> 4) + wave * 2;     // wave's two A row-tiles
  const int brt0 = (c0 >> 4);                // block's four B col-tiles

  f32x4 acc[2][4];
#pragma unroll
  for (int m = 0; m < 2; ++m)
#pragma unroll
    for (int n = 0; n < 4; ++n) acc[m][n] = (f32x4){0.f, 0.f, 0.f, 0.f};

#pragma unroll 4
  for (int s = 0; s < NSL; ++s) {            // 16 k-slices, no LDS, no barriers
    bf16x8 aF[2], bF[4];
#pragma unroll
    for (int m = 0; m < 2; ++m)
      aF[m] = *(const bf16x8*)(zf + frag_off_us(art0 + m, s, lane));
#pragma unroll
    for (int n = 0; n < 4; ++n)
      bF[n] = *(const bf16x8*)(zf + frag_off_us(brt0 + n, s, lane));
#pragma unroll
    for (int m = 0; m < 2; ++m)
#pragma unroll
      for (int n = 0; n < 4; ++n)
        acc[m][n] = __builtin_amdgcn_mfma_f32_16x16x32_bf16(aF[m], bF[n], acc[m][n], 0, 0, 0);
  }

  // ---- epilogue: fused exp-sum / rank-count, both directions ----
  int growv[8], gpartr[8];
  float pvr[8];
#pragma unroll
  for (int m = 0; m < 2; ++m)
#pragma unroll
    for (int reg = 0; reg < 4; ++reg) {
      int idx = m * 4 + reg;
      int grow = r0 + wave * 32 + m * 16 + g * 4 + reg;
      growv[idx] = grow;
      gpartr[idx] = (grow < B) ? grow + B : grow - B;
      pvr[idx] = pos[grow];
    }
  int gcolv[4], gpartc[4];
  float pvc[4];
#pragma unroll
  for (int n = 0; n < 4; ++n) {
    int gcol = c0 + n * 16 + cl;
    gcolv[n] = gcol;
    gpartc[n] = (gcol < B) ? gcol + B : gcol - B;
    pvc[n] = pos[gcol];
  }

  float ssr[8], ccr[8], ssc[4], ccc[4];
#pragma unroll
  for (int i = 0; i < 8; ++i) { ssr[i] = 0.f; ccr[i] = 0.f; }
#pragma unroll
  for (int n = 0; n < 4; ++n) { ssc[n] = 0.f; ccc[n] = 0.f; }

#pragma unroll
  for (int m = 0; m < 2; ++m)
#pragma unroll
    for (int n = 0; n < 4; ++n)
#pragma unroll
      for (int reg = 0; reg < 4; ++reg) {
        const int idx = m * 4 + reg;
        float val = acc[m][n][reg] * invt;
        float e = __expf(val);
        bool isd = diag && (gcolv[n] == growv[idx]);
        if (!isd) {
          ssr[idx] += e;
          ccr[idx] += (gcolv[n] != gpartr[idx] && val > pvr[idx]) ? 1.f : 0.f;
        }
        if (!diag) {
          ssc[n] += e;
          ccc[n] += (growv[idx] != gpartc[n] && val > pvc[n]) ? 1.f : 0.f;
        }
      }

  // row partials: rows live wholly in-wave -> reduce over cl, write chunk bj
#pragma unroll
  for (int idx = 0; idx < 8; ++idx) {
    float s = ssr[idx], c = ccr[idx];
#pragma unroll
    for (int off = 1; off < 16; off <<= 1) {
      s += __shfl_xor(s, off, 64);
      c += __shfl_xor(c, off, 64);
    }
    if (cl == 0) {
      partS[(size_t)growv[idx] * NCH + bj] = s;
      partC[(size_t)growv[idx] * NCH + bj] = c;
    }
  }

  // col partials: reduce over g in-wave, cross-wave combine via tiny LDS
  __shared__ float cbuf[256];                 // [0..127] S, [128..255] C
  if (!diag) {
#pragma unroll
    for (int n = 0; n < 4; ++n) {
      ssc[n] += __shfl_xor(ssc[n], 16, 64); ccc[n] += __shfl_xor(ccc[n], 16, 64);
      ssc[n] += __shfl_xor(ssc[n], 32, 64); ccc[n] += __shfl_xor(ccc[n], 32, 64);
    }
    if (g == 0) {
#pragma unroll
      for (int n = 0; n < 4; ++n) {
        cbuf[wave * 64 + n * 16 + cl] = ssc[n];
        cbuf[128 + wave * 64 + n * 16 + cl] = ccc[n];
      }
    }
  }
  __syncthreads();
  if (!diag && t < 64) {
    float s = cbuf[t] + cbuf[64 + t];
    float c = cbuf[128 + t] + cbuf[192 + t];
    partS[(size_t)(c0 + t) * NCH + bi] = s;
    partC[(size_t)(c0 + t) * NCH + bi] = c;
  }
}

// ---- kernel 3: per-row combine of 64 chunks -> rowLoss, rowCnt ----
__global__ void k_rowfin(const float* __restrict__ partS, const float* __restrict__ partC,
                         const float* __restrict__ pos, float* __restrict__ rowL,
                         float* __restrict__ rowC, int N) {
  int r = (blockIdx.x * blockDim.x + threadIdx.x) >> 6;
  int lane = threadIdx.x & 63;
  if (r >= N) return;
  float s = partS[(size_t)r * NCH + lane];
  float c = partC[(size_t)r * NCH + lane];
#pragma unroll
  for (int off = 32; off; off >>= 1) { s += __shfl_xor(s, off, 64); c += __shfl_xor(c, off, 64); }
  if (lane == 0) {
    rowL[r] = logf(s) - pos[r];
    rowC[r] = c;
  }
}

// ---- kernel 4: final reduction to (loss, avg_rank) ----
__global__ void k_final(const float* __restrict__ rowL, const float* __restrict__ rowC,
                        float* __restrict__ out, int N) {
  float ls = 0.f, cs = 0.f;
  for (int r = threadIdx.x; r < N; r += 256) { ls += rowL[r]; cs += rowC[r]; }
  __shared__ float l[256], c[256];
  l[threadIdx.x] = ls; c[threadIdx.x] = cs;
  __syncthreads();
  for (int off = 128; off; off >>= 1) {
    if (threadIdx.x < off) { l[threadIdx.x] += l[threadIdx.x + off]; c[threadIdx.x] += c[threadIdx.x + off]; }
    __syncthreads();
  }
  if (threadIdx.x == 0) { out[0] = l[0] / (float)N; out[1] = c[0] / (float)N; }
}

extern "C" void kernel_launch(void* const* d_in, const int* in_sizes, int n_in,
                              void* d_out, int out_size, void* d_ws, size_t ws_size,
                              hipStream_t stream) {
  const float* zi = (const float*)d_in[0];
  const float* zj = (const float*)d_in[1];
  const float* temp = (const float*)d_in[2];
  float* out = (float*)d_out;

  const int B = in_sizes[0] / DDIM;   // 2048
  const int N = 2 * B;                // 4096

  unsigned short* zf = (unsigned short*)d_ws;           // N*DDIM bf16, frag-major
  float* fws = (float*)(zf + (size_t)N * DDIM);
  float* pos   = fws;                                    // N
  float* partS = pos + N;                                // N*NCH = 1 MB
  float* partC = partS + (size_t)N * NCH;                // N*NCH = 1 MB
  float* rowL  = partC + (size_t)N * NCH;                // N
  float* rowC  = rowL + N;                               // N

  k_prep<<<(B * 64) / 256, 256, 0, stream>>>(zi, zj, temp, zf, pos, B);
  k_main<<<NTILES, THREADS, 0, stream>>>(zf, pos, temp, partS, partC, B);
  k_rowfin<<<(N * 64) / 256, 256, 0, stream>>>(partS, partC, pos, rowL, rowC, N);
  k_final<<<1, 256, 0, stream>>>(rowL, rowC, out, N);
}